// Round 8
// baseline (2259.214 us; speedup 1.0000x reference)
//
#include <hip/hip_runtime.h>
#include <math.h>

#define B_T   128
#define NS    128
#define NQ    512
#define DIN   256
#define DOUT  64

#define MU_SIZE  (B_T*NQ*DOUT)            // 4,194,304 floats
#define SIG_SIZE (B_T*NQ*DOUT*DOUT)       // 268,435,456 floats
#define NLL_IDX  (MU_SIZE + SIG_SIZE)     // 272,629,760

typedef double v4df __attribute__((ext_vector_type(4)));

// D-layout candidates for f64 MFMA (see probe)
__device__ __forceinline__ void dmap(int fl, int kq, int mrow, int rr,
                                     int& lr, int& lc) {
    if (fl == 0)      { lr = kq * 4 + rr; lc = mrow; }
    else if (fl == 1) { lr = kq + 4 * rr; lc = mrow; }
    else if (fl == 2) { lr = mrow; lc = kq * 4 + rr; }
    else              { lr = mrow; lc = kq + 4 * rr; }
}

// ---------------------------------------------------------------------------
// PROBE: verify f64 MFMA fragment contract; flag 99 = scalar fallback.
// ---------------------------------------------------------------------------
__global__ void k_mfma_probe(double* __restrict__ FLAGD) {
    int l = threadIdx.x;
    int m = l & 15, q = l >> 4;
    double a = (double)(1 + m + 2 * q);
    double b = (double)(1 + 3 * m + 5 * q);
    v4df d = {0.0, 0.0, 0.0, 0.0};
    d = __builtin_amdgcn_mfma_f64_16x16x4f64(a, b, d, 0, 0, 0);
    bool ok0 = true, ok1 = true, ok2 = true, ok3 = true;
#pragma unroll
    for (int r = 0; r < 4; ++r) {
        int rows[4] = {4 * q + r, q + 4 * r, m, m};
        int cols[4] = {m, m, 4 * q + r, q + 4 * r};
        double ref[4];
#pragma unroll
        for (int v = 0; v < 4; ++v) {
            double s = 0.0;
#pragma unroll
            for (int k = 0; k < 4; ++k)
                s += (double)(1 + rows[v] + 2 * k) * (double)(1 + 3 * cols[v] + 5 * k);
            ref[v] = s;
        }
        if (d[r] != ref[0]) ok0 = false;
        if (d[r] != ref[1]) ok1 = false;
        if (d[r] != ref[2]) ok2 = false;
        if (d[r] != ref[3]) ok3 = false;
    }
    ok0 = __all(ok0); ok1 = __all(ok1); ok2 = __all(ok2); ok3 = __all(ok3);
    if (l == 0) {
        double f = 99.0;
        if (ok0) f = 0.0;
        else if (ok1) f = 1.0;
        else if (ok2) f = 2.0;
        else if (ok3) f = 3.0;
        FLAGD[0] = f;
    }
}

// ---------------------------------------------------------------------------
// K0a: Sp = A @ A^T  (fp64 accumulate); also zeroes the NLL accumulator.
// ---------------------------------------------------------------------------
__global__ __launch_bounds__(256) void k_prior_sp(const float* __restrict__ A,
                                                  double* __restrict__ Sp,
                                                  double* __restrict__ NLLACC) {
    __shared__ float Ai[16][260];
    __shared__ float Aj[16][260];
    int bi = blockIdx.x;
    int i0 = (bi >> 4) << 4;
    int j0 = (bi & 15) << 4;
    int tid = threadIdx.x;
    if (bi == 0 && tid == 0) NLLACC[0] = 0.0;
    for (int idx = tid; idx < 16 * 256; idx += 256) {
        int r = idx >> 8, c = idx & 255;
        Ai[r][c] = A[(i0 + r) * 256 + c];
        Aj[r][c] = A[(j0 + r) * 256 + c];
    }
    __syncthreads();
    int r = tid >> 4, c = tid & 15;
    double acc = 0.0;
    for (int k = 0; k < 256; ++k)
        acc += (double)Ai[r][k] * (double)Aj[c][k];
    Sp[(i0 + r) * 256 + (j0 + c)] = acc;
}

// ---------------------------------------------------------------------------
// K0b: MPN = Sp @ m_prior
// ---------------------------------------------------------------------------
__global__ __launch_bounds__(64) void k_prior_mpn(const double* __restrict__ Sp,
                                                  const float* __restrict__ MP,
                                                  double* __restrict__ MPN) {
    int i = blockIdx.x, k = threadIdx.x;
    double acc = 0.0;
    for (int t = 0; t < 256; ++t)
        acc += Sp[i * 256 + t] * (double)MP[t * 64 + k];
    MPN[i * 64 + k] = acc;
}

// ---------------------------------------------------------------------------
// K1: G_b = Phi_s^T Phi_s + Sp  (lower-triangle 64x64 tiles, dual-path).
// ---------------------------------------------------------------------------
__global__ __launch_bounds__(256) void k_build_G(const float* __restrict__ PHI,
                                                 const double* __restrict__ Sp,
                                                 double* __restrict__ G,
                                                 const double* __restrict__ FLAGD) {
    __shared__ float As[128][64];
    __shared__ float Bs[128][64];
    int b = blockIdx.x;
    int by = blockIdx.y;
    int ti = 0;
    while (((ti + 1) * (ti + 2)) / 2 <= by) ti++;
    int tj = by - (ti * (ti + 1)) / 2;
    int i0 = ti * 64, j0 = tj * 64;
    int tid = threadIdx.x;
    const float* Pb = PHI + b * (NS * DIN);
    for (int idx = tid; idx < 128 * 64; idx += 256) {
        int n = idx >> 6, c = idx & 63;
        As[n][c] = Pb[n * 256 + i0 + c];
        Bs[n][c] = Pb[n * 256 + j0 + c];
    }
    __syncthreads();
    double* Gb = G + b * 65536;
    int fl = (int)FLAGD[0];
    if (fl < 4) {
        int lane = tid & 63, w = tid >> 6;
        int mrow = lane & 15, kq = lane >> 4;
        v4df acc[4];
#pragma unroll
        for (int t = 0; t < 4; ++t) acc[t] = (v4df){0.0, 0.0, 0.0, 0.0};
        for (int ks = 0; ks < 128; ks += 4) {
            double a = (double)As[ks + kq][w * 16 + mrow];
#pragma unroll
            for (int t = 0; t < 4; ++t) {
                double bb = (double)Bs[ks + kq][t * 16 + mrow];
                acc[t] = __builtin_amdgcn_mfma_f64_16x16x4f64(a, bb, acc[t], 0, 0, 0);
            }
        }
#pragma unroll
        for (int t = 0; t < 4; ++t) {
#pragma unroll
            for (int rr = 0; rr < 4; ++rr) {
                int lr, lc; dmap(fl, kq, mrow, rr, lr, lc);
                int i = i0 + w * 16 + lr;
                int j = j0 + t * 16 + lc;
                Gb[i * 256 + j] = acc[t][rr] + Sp[i * 256 + j];
            }
        }
    } else {
        int tx = tid & 15, ty = tid >> 4;
        double acc[4][4];
#pragma unroll
        for (int r = 0; r < 4; ++r)
#pragma unroll
            for (int s = 0; s < 4; ++s) acc[r][s] = 0.0;
        for (int n = 0; n < 128; ++n) {
            float a0 = As[n][4 * ty + 0], a1 = As[n][4 * ty + 1];
            float a2 = As[n][4 * ty + 2], a3 = As[n][4 * ty + 3];
            float b0 = Bs[n][4 * tx + 0], b1 = Bs[n][4 * tx + 1];
            float b2 = Bs[n][4 * tx + 2], b3 = Bs[n][4 * tx + 3];
            acc[0][0] += (double)a0 * b0; acc[0][1] += (double)a0 * b1;
            acc[0][2] += (double)a0 * b2; acc[0][3] += (double)a0 * b3;
            acc[1][0] += (double)a1 * b0; acc[1][1] += (double)a1 * b1;
            acc[1][2] += (double)a1 * b2; acc[1][3] += (double)a1 * b3;
            acc[2][0] += (double)a2 * b0; acc[2][1] += (double)a2 * b1;
            acc[2][2] += (double)a2 * b2; acc[2][3] += (double)a2 * b3;
            acc[3][0] += (double)a3 * b0; acc[3][1] += (double)a3 * b1;
            acc[3][2] += (double)a3 * b2; acc[3][3] += (double)a3 * b3;
        }
#pragma unroll
        for (int r = 0; r < 4; ++r) {
            int i = i0 + 4 * ty + r;
#pragma unroll
            for (int s = 0; s < 4; ++s) {
                int j = j0 + 4 * tx + s;
                Gb[i * 256 + j] = acc[r][s] + Sp[i * 256 + j];
            }
        }
    }
}

// ---------------------------------------------------------------------------
// K2: RHS_b = Phi_s^T Y_s + MPN  (dual-path)
// ---------------------------------------------------------------------------
__global__ __launch_bounds__(256) void k_build_rhs(const float* __restrict__ PHI,
                                                   const float* __restrict__ Y,
                                                   const double* __restrict__ MPN,
                                                   double* __restrict__ RHS,
                                                   const double* __restrict__ FLAGD) {
    __shared__ float As[128][64];
    __shared__ float Ys[128][64];
    int b = blockIdx.x, i0 = blockIdx.y * 64, tid = threadIdx.x;
    const float* Pb = PHI + b * (NS * DIN);
    const float* Yb = Y + b * (NS * DOUT);
    for (int idx = tid; idx < 128 * 64; idx += 256) {
        int n = idx >> 6, c = idx & 63;
        As[n][c] = Pb[n * 256 + i0 + c];
        Ys[n][c] = Yb[n * 64 + c];
    }
    __syncthreads();
    double* Rb = RHS + b * 16384;
    int fl = (int)FLAGD[0];
    if (fl < 4) {
        int lane = tid & 63, w = tid >> 6;
        int mrow = lane & 15, kq = lane >> 4;
        v4df acc[4];
#pragma unroll
        for (int t = 0; t < 4; ++t) acc[t] = (v4df){0.0, 0.0, 0.0, 0.0};
        for (int ks = 0; ks < 128; ks += 4) {
            double a = (double)As[ks + kq][w * 16 + mrow];
#pragma unroll
            for (int t = 0; t < 4; ++t) {
                double bb = (double)Ys[ks + kq][t * 16 + mrow];
                acc[t] = __builtin_amdgcn_mfma_f64_16x16x4f64(a, bb, acc[t], 0, 0, 0);
            }
        }
#pragma unroll
        for (int t = 0; t < 4; ++t) {
#pragma unroll
            for (int rr = 0; rr < 4; ++rr) {
                int lr, lc; dmap(fl, kq, mrow, rr, lr, lc);
                int i = i0 + w * 16 + lr;
                int kc = t * 16 + lc;
                Rb[i * 64 + kc] = acc[t][rr] + MPN[i * 64 + kc];
            }
        }
    } else {
        int tx = tid & 15, ty = tid >> 4;
        double acc[4][4];
#pragma unroll
        for (int r = 0; r < 4; ++r)
#pragma unroll
            for (int s = 0; s < 4; ++s) acc[r][s] = 0.0;
        for (int n = 0; n < 128; ++n) {
            float a0 = As[n][4 * ty + 0], a1 = As[n][4 * ty + 1];
            float a2 = As[n][4 * ty + 2], a3 = As[n][4 * ty + 3];
            float y0 = Ys[n][4 * tx + 0], y1 = Ys[n][4 * tx + 1];
            float y2 = Ys[n][4 * tx + 2], y3 = Ys[n][4 * tx + 3];
            acc[0][0] += (double)a0 * y0; acc[0][1] += (double)a0 * y1;
            acc[0][2] += (double)a0 * y2; acc[0][3] += (double)a0 * y3;
            acc[1][0] += (double)a1 * y0; acc[1][1] += (double)a1 * y1;
            acc[1][2] += (double)a1 * y2; acc[1][3] += (double)a1 * y3;
            acc[2][0] += (double)a2 * y0; acc[2][1] += (double)a2 * y1;
            acc[2][2] += (double)a2 * y2; acc[2][3] += (double)a2 * y3;
            acc[3][0] += (double)a3 * y0; acc[3][1] += (double)a3 * y1;
            acc[3][2] += (double)a3 * y2; acc[3][3] += (double)a3 * y3;
        }
#pragma unroll
        for (int r = 0; r < 4; ++r) {
            int i = i0 + 4 * ty + r;
#pragma unroll
            for (int s = 0; s < 4; ++s) {
                int kc = 4 * tx + s;
                Rb[i * 64 + kc] = acc[r][s] + MPN[i * 64 + kc];
            }
        }
    }
}

// ---------------------------------------------------------------------------
// K3: FUSED blocked Cholesky, NB=64, ONE block per task, ONE dispatch.
//     Per kb: potrf64-in-LDS (proven internals) -> LI build -> TRSM row
//     tiles -> SYRK pairs. 64 KB LDS phase-unioned; G RMW'd once/elem/kb.
//     Replaces the 10-dispatch potrf/trsm/syrk chain.
// ---------------------------------------------------------------------------
__global__ __launch_bounds__(256) void k_cholf(double* __restrict__ G,
                                               double* __restrict__ LT,
                                               double* __restrict__ LI) {
    __shared__ double S[8192];     // 64 KB, partitioned per phase
#define DD(r, c)  S[(r) * 65 + (c)]          // [0, 4160)   diag work tile
#define TT(i, j)  S[4160 + (i) * 33 + (j)]   // [4160,6272) T11 (rows 0-31) / T22
#define CC(r, c)  S[6272 + (r) * 33 + (c)]   // [6272,7328) L21@T11 scratch
    double* LL = S + 7328;                    // 16*17 factored diag16
    double* DV = S + 7600;                    // 16 inv-diag
    double* S1 = S;                           // [0,4096)   LIs / Li (SYRK)
    double* S2 = S + 4096;                    // [4096,8192) G21t / Lj (SYRK)
    int b = blockIdx.x, tid = threadIdx.x;
    double* Gb = G + b * 65536;
    double* LTb = LT + b * 65536;
    double* LIbase = LI + b * 16384;

    for (int kb = 0; kb < 4; ++kb) {
        int o = kb * 64;
        double* LIb = LIbase + kb * 4096;
        // ---- phase 1: stage diag block (coalesced) ----
        for (int idx = tid; idx < 4096; idx += 256) {
            int r = idx >> 6, c = idx & 63;
            DD(r, c) = Gb[(o + r) * 256 + o + c];
        }
        __syncthreads();
        // ---- phase 2: factor 64x64 in LDS (proven potrf64 internals) ----
        for (int p0 = 0; p0 < 64; p0 += 16) {
            if (tid < 64) {
                int lane = tid;
                double a[16];
                if (lane < 16) {
#pragma unroll
                    for (int p = 0; p < 16; ++p) a[p] = DD(p0 + lane, p0 + p);
                }
#pragma unroll
                for (int p = 0; p < 16; ++p) {
                    double dp = __shfl(a[p], p);
                    double d = sqrt(fmax(dp, 1e-300));
                    double inv = 1.0 / d;
                    if (lane == p) { a[p] = d; DV[p] = inv; }
                    else if (lane > p) a[p] *= inv;
#pragma unroll
                    for (int p2 = p + 1; p2 < 16; ++p2) {
                        double cc = __shfl(a[p], p2);
                        if (lane > p) a[p2] -= a[p] * cc;
                    }
                }
                if (lane < 16) {
#pragma unroll
                    for (int p = 0; p < 16; ++p) {
                        if (p <= lane) {
                            LL[lane * 17 + p] = a[p];
                            DD(p0 + lane, p0 + p) = a[p];
                        }
                    }
                }
            }
            __syncthreads();
            int nsolve = 48 - p0;
            if (tid < nsolve) {
                int rr = p0 + 16 + tid;
                double x[16];
#pragma unroll
                for (int p = 0; p < 16; ++p) {
                    double s = DD(rr, p0 + p);
#pragma unroll
                    for (int p2 = 0; p2 < 16; ++p2) {
                        if (p2 < p) s -= LL[p * 17 + p2] * x[p2];
                    }
                    x[p] = s * DV[p];
                    DD(rr, p0 + p) = x[p];
                }
            }
            __syncthreads();
            int rem = nsolve;
            for (int idx = tid; idx < rem * rem; idx += 256) {
                int i2 = idx / rem, j2 = idx - i2 * rem;
                if (j2 <= i2) {
                    int i = p0 + 16 + i2, j = p0 + 16 + j2;
                    double s = 0.0;
#pragma unroll
                    for (int p = 0; p < 16; ++p) s += DD(i, p0 + p) * DD(j, p0 + p);
                    DD(i, j) -= s;
                }
            }
            __syncthreads();
        }
        // write L11 to LT (coalesced along r)
        for (int idx = tid; idx < 4096; idx += 256) {
            int c = idx >> 6, r = idx & 63;
            if (r >= c) LTb[(o + c) * 256 + (o + r)] = DD(r, c);
        }
        // invert 32x32 diag sub-blocks -> TT (proven diaginv pattern)
        if (tid < 64) {
            int g = tid >> 5, j = tid & 31;
            int off = g * 32;
            double x[32];
#pragma unroll
            for (int i = 0; i < 32; ++i) {
                double s = (i == j) ? 1.0 : 0.0;
#pragma unroll
                for (int k = 0; k < i; ++k) {
                    double lv = DD(off + i, off + k);
                    s -= (k >= j) ? lv * x[k] : 0.0;
                }
                double inv = 1.0 / DD(off + i, off + i);
                x[i] = (i >= j) ? s * inv : 0.0;
            }
#pragma unroll
            for (int i = 0; i < 32; ++i) TT(off + i, j) = x[i];
        }
        __syncthreads();
        // C = L21 @ T11
        for (int idx = tid; idx < 1024; idx += 256) {
            int r = idx >> 5, c = idx & 31;
            double s = 0.0;
#pragma unroll
            for (int p = 0; p < 32; ++p) s += DD(32 + r, p) * TT(p, c);
            CC(r, c) = s;
        }
        __syncthreads();
        // X21 = -T22 @ C -> DD rows 32..63 cols 0..31
        for (int idx = tid; idx < 1024; idx += 256) {
            int r = idx >> 5, c = idx & 31;
            double s = 0.0;
#pragma unroll
            for (int p = 0; p < 32; ++p) s += TT(32 + r, p) * CC(p, c);
            DD(32 + r, c) = -s;
        }
        __syncthreads();
        // ---- phase 3: build LIs[p][c] = Linv[c][p] via regs (overlap-safe) ----
        double v[16];
#pragma unroll
        for (int u = 0; u < 16; ++u) {
            int idx = tid + u * 256;
            int p = idx >> 6, c = idx & 63;
            v[u] = (c < 32) ? ((p < 32) ? TT(c, p) : 0.0)
                            : ((p < 32) ? DD(c, p) : TT(c, p - 32));
        }
        __syncthreads();
#pragma unroll
        for (int u = 0; u < 16; ++u) S1[tid + u * 256] = v[u];
        __syncthreads();
        for (int idx = tid; idx < 4096; idx += 256) LIb[idx] = S1[idx];
        // ---- phase 4: TRSM row tiles: L21 = G21 @ L11^{-T} ----
        for (int rb = kb + 1; rb < 4; ++rb) {
            int i0 = rb * 64;
            // transpose-stage G21: S2[kk*64+r] = G[i0+r][o+kk] (coalesced read)
            for (int idx = tid; idx < 4096; idx += 256) {
                int r = idx >> 6, kk = idx & 63;
                S2[kk * 64 + r] = Gb[(i0 + r) * 256 + o + kk];
            }
            __syncthreads();
            int tx = tid & 15, ty = tid >> 4;
            double acc[4][4];
#pragma unroll
            for (int r = 0; r < 4; ++r)
#pragma unroll
                for (int s = 0; s < 4; ++s) acc[r][s] = 0.0;
            for (int kk = 0; kk < 64; ++kk) {
                double a0 = S2[kk * 64 + 4 * ty + 0], a1 = S2[kk * 64 + 4 * ty + 1];
                double a2 = S2[kk * 64 + 4 * ty + 2], a3 = S2[kk * 64 + 4 * ty + 3];
                double b0 = S1[kk * 64 + 4 * tx + 0], b1 = S1[kk * 64 + 4 * tx + 1];
                double b2 = S1[kk * 64 + 4 * tx + 2], b3 = S1[kk * 64 + 4 * tx + 3];
                acc[0][0] += a0 * b0; acc[0][1] += a0 * b1; acc[0][2] += a0 * b2; acc[0][3] += a0 * b3;
                acc[1][0] += a1 * b0; acc[1][1] += a1 * b1; acc[1][2] += a1 * b2; acc[1][3] += a1 * b3;
                acc[2][0] += a2 * b0; acc[2][1] += a2 * b1; acc[2][2] += a2 * b2; acc[2][3] += a2 * b3;
                acc[3][0] += a3 * b0; acc[3][1] += a3 * b1; acc[3][2] += a3 * b2; acc[3][3] += a3 * b3;
            }
#pragma unroll
            for (int r = 0; r < 4; ++r)
#pragma unroll
                for (int s = 0; s < 4; ++s)
                    LTb[(o + 4 * tx + s) * 256 + i0 + 4 * ty + r] = acc[r][s];
            __syncthreads();
        }
        // ---- phase 5: SYRK pairs: G[ti][tj] -= L21[ti] @ L21[tj]^T ----
        for (int ti2 = kb + 1; ti2 < 4; ++ti2) {
            for (int tj2 = kb + 1; tj2 <= ti2; ++tj2) {
                int i0 = ti2 * 64, j0 = tj2 * 64;
                for (int idx = tid; idx < 4096; idx += 256) {
                    int p = idx >> 6, r = idx & 63;
                    S1[idx] = LTb[(o + p) * 256 + i0 + r];   // Li [k][r]
                    S2[idx] = LTb[(o + p) * 256 + j0 + r];   // Lj [k][c]
                }
                __syncthreads();
                int tx = tid & 15, ty = tid >> 4;
                double acc[4][4];
#pragma unroll
                for (int r = 0; r < 4; ++r)
#pragma unroll
                    for (int s = 0; s < 4; ++s) acc[r][s] = 0.0;
                for (int kk = 0; kk < 64; ++kk) {
                    double a0 = S1[kk * 64 + 4 * ty + 0], a1 = S1[kk * 64 + 4 * ty + 1];
                    double a2 = S1[kk * 64 + 4 * ty + 2], a3 = S1[kk * 64 + 4 * ty + 3];
                    double b0 = S2[kk * 64 + 4 * tx + 0], b1 = S2[kk * 64 + 4 * tx + 1];
                    double b2 = S2[kk * 64 + 4 * tx + 2], b3 = S2[kk * 64 + 4 * tx + 3];
                    acc[0][0] += a0 * b0; acc[0][1] += a0 * b1; acc[0][2] += a0 * b2; acc[0][3] += a0 * b3;
                    acc[1][0] += a1 * b0; acc[1][1] += a1 * b1; acc[1][2] += a1 * b2; acc[1][3] += a1 * b3;
                    acc[2][0] += a2 * b0; acc[2][1] += a2 * b1; acc[2][2] += a2 * b2; acc[2][3] += a2 * b3;
                    acc[3][0] += a3 * b0; acc[3][1] += a3 * b1; acc[3][2] += a3 * b2; acc[3][3] += a3 * b3;
                }
#pragma unroll
                for (int r = 0; r < 4; ++r) {
                    int gi = i0 + 4 * ty + r;
#pragma unroll
                    for (int s = 0; s < 4; ++s) {
                        int gj = j0 + 4 * tx + s;
                        Gb[gi * 256 + gj] -= acc[r][s];
                    }
                }
                __syncthreads();
            }
        }
    }
#undef DD
#undef TT
#undef CC
}

// ---------------------------------------------------------------------------
// K3b: TI/TIF diag tiles from LI (+ zero uppers); zero the 6 upper 64-tiles.
// ---------------------------------------------------------------------------
__global__ __launch_bounds__(256) void k_tidiag(const double* __restrict__ LI,
                                                double* __restrict__ TI,
                                                float* __restrict__ TIF) {
    __shared__ double Ls[4096];
    int b = blockIdx.x, tid = threadIdx.x;
    const double* LIbase = LI + b * 16384;
    double* TIb = TI + b * 65536;
    float* TIFb = TIF + b * 65536;
    const int tis[6] = {0, 0, 0, 1, 1, 2};
    const int tjs[6] = {1, 2, 3, 2, 3, 3};
    for (int t = 0; t < 6; ++t) {
        int o_i = tis[t] * 64, o_j = tjs[t] * 64;
        for (int idx = tid; idx < 4096; idx += 256) {
            int r = idx >> 6, c = idx & 63;
            TIb[(o_i + r) * 256 + o_j + c] = 0.0;
            TIFb[(o_i + r) * 256 + o_j + c] = 0.0f;
        }
    }
    for (int kb = 0; kb < 4; ++kb) {
        for (int idx = tid; idx < 4096; idx += 256) Ls[idx] = LIbase[kb * 4096 + idx];
        __syncthreads();
        int o = kb * 64;
        for (int idx = tid; idx < 4096; idx += 256) {
            int r = idx >> 6, c = idx & 63;
            double vv = (c <= r) ? Ls[c * 64 + r] : 0.0;   // Linv[r][c]
            TIb[(o + r) * 256 + o + c] = vv;
            TIFb[(o + r) * 256 + o + c] = (float)vv;
        }
        __syncthreads();
    }
}

// ---------------------------------------------------------------------------
// K3c: trinv with 64-blocking, column-parallel: grid (B, 3).
//      X_IJ = -LI_I @ (sum_{K=J}^{I-1} L_IK @ X_KJ), X_JJ from TI (tidiag).
// ---------------------------------------------------------------------------
__global__ __launch_bounds__(256) void k_trinv64(const double* __restrict__ LT,
                                                 const double* __restrict__ LI,
                                                 double* __restrict__ TI,
                                                 float* __restrict__ TIF) {
    __shared__ double A1[4096];   // L_IK / LI_I as [k][r]
    __shared__ double A2[4096];   // X_KJ as [k][c] / W
    int b = blockIdx.x, J = blockIdx.y;              // J in 0..2
    int tid = threadIdx.x, tx = tid & 15, ty = tid >> 4;
    const double* LTb = LT + b * 65536;
    const double* LIbase = LI + b * 16384;
    double* TIb = TI + b * 65536;
    float* TIFb = TIF + b * 65536;
    int oJ = J * 64;
    for (int I = J + 1; I < 4; ++I) {
        int oI = I * 64;
        double acc[4][4];
#pragma unroll
        for (int r = 0; r < 4; ++r)
#pragma unroll
            for (int s = 0; s < 4; ++s) acc[r][s] = 0.0;
        for (int K = J; K < I; ++K) {
            int oK = K * 64;
            for (int idx = tid; idx < 4096; idx += 256) {
                int k = idx >> 6, x = idx & 63;
                A1[idx] = LTb[(oK + k) * 256 + oI + x];   // L_IK[x][k] -> [k][x]
                A2[idx] = TIb[(oK + k) * 256 + oJ + x];   // X_KJ[k][x]
            }
            __syncthreads();
            for (int kk = 0; kk < 64; ++kk) {
                double a0 = A1[kk * 64 + 4 * ty + 0], a1 = A1[kk * 64 + 4 * ty + 1];
                double a2 = A1[kk * 64 + 4 * ty + 2], a3 = A1[kk * 64 + 4 * ty + 3];
                double b0 = A2[kk * 64 + 4 * tx + 0], b1 = A2[kk * 64 + 4 * tx + 1];
                double b2 = A2[kk * 64 + 4 * tx + 2], b3 = A2[kk * 64 + 4 * tx + 3];
                acc[0][0] += a0 * b0; acc[0][1] += a0 * b1; acc[0][2] += a0 * b2; acc[0][3] += a0 * b3;
                acc[1][0] += a1 * b0; acc[1][1] += a1 * b1; acc[1][2] += a1 * b2; acc[1][3] += a1 * b3;
                acc[2][0] += a2 * b0; acc[2][1] += a2 * b1; acc[2][2] += a2 * b2; acc[2][3] += a2 * b3;
                acc[3][0] += a3 * b0; acc[3][1] += a3 * b1; acc[3][2] += a3 * b2; acc[3][3] += a3 * b3;
            }
            __syncthreads();
        }
        // W -> A2 ([k][c]); stage LI_I (linear copy: A1[k][r] = Linv_I[r][k])
#pragma unroll
        for (int r = 0; r < 4; ++r)
#pragma unroll
            for (int s = 0; s < 4; ++s)
                A2[(4 * ty + r) * 64 + 4 * tx + s] = acc[r][s];
        for (int idx = tid; idx < 4096; idx += 256)
            A1[idx] = LIbase[I * 4096 + idx];
        __syncthreads();
        double c2[4][4];
#pragma unroll
        for (int r = 0; r < 4; ++r)
#pragma unroll
            for (int s = 0; s < 4; ++s) c2[r][s] = 0.0;
        for (int kk = 0; kk < 64; ++kk) {
            double a0 = A1[kk * 64 + 4 * ty + 0], a1 = A1[kk * 64 + 4 * ty + 1];
            double a2 = A1[kk * 64 + 4 * ty + 2], a3 = A1[kk * 64 + 4 * ty + 3];
            double b0 = A2[kk * 64 + 4 * tx + 0], b1 = A2[kk * 64 + 4 * tx + 1];
            double b2 = A2[kk * 64 + 4 * tx + 2], b3 = A2[kk * 64 + 4 * tx + 3];
            c2[0][0] += a0 * b0; c2[0][1] += a0 * b1; c2[0][2] += a0 * b2; c2[0][3] += a0 * b3;
            c2[1][0] += a1 * b0; c2[1][1] += a1 * b1; c2[1][2] += a1 * b2; c2[1][3] += a1 * b3;
            c2[2][0] += a2 * b0; c2[2][1] += a2 * b1; c2[2][2] += a2 * b2; c2[2][3] += a2 * b3;
            c2[3][0] += a3 * b0; c2[3][1] += a3 * b1; c2[3][2] += a3 * b2; c2[3][3] += a3 * b3;
        }
#pragma unroll
        for (int r = 0; r < 4; ++r) {
            int gi = oI + 4 * ty + r;
#pragma unroll
            for (int s = 0; s < 4; ++s) {
                int gj = oJ + 4 * tx + s;
                double xv = -c2[r][s];
                TIb[gi * 256 + gj] = xv;
                TIFb[gi * 256 + gj] = (float)xv;
            }
        }
        __syncthreads();
    }
}

// ---------------------------------------------------------------------------
// K4a: Z = Tinv @ RHS  (dual-path, 64-row tiles, triangular k-skip)
// ---------------------------------------------------------------------------
__global__ __launch_bounds__(256) void k_gemm_Z(const double* __restrict__ TI,
                                                const double* __restrict__ RHS,
                                                double* __restrict__ Z,
                                                const double* __restrict__ FLAGD) {
    __shared__ double As[64][65];   // [m][k]
    __shared__ double Bs[64][65];   // [k][c]
    int b = blockIdx.x, i0 = blockIdx.y * 64;
    int tid = threadIdx.x;
    const double* TIb = TI + b * 65536;
    const double* Rb = RHS + b * 16384;
    double* Zb = Z + b * 16384;
    int fl = (int)FLAGD[0];
    if (fl < 4) {
        int lane = tid & 63, w = tid >> 6;
        int mrow = lane & 15, kq = lane >> 4;
        v4df acc[4];
#pragma unroll
        for (int t = 0; t < 4; ++t) acc[t] = (v4df){0.0, 0.0, 0.0, 0.0};
        for (int k0 = 0; k0 <= i0; k0 += 64) {
            for (int idx = tid; idx < 4096; idx += 256) {
                int r = idx >> 6, kk = idx & 63;
                As[r][kk] = TIb[(i0 + r) * 256 + k0 + kk];
                Bs[r][kk] = Rb[(k0 + r) * 64 + kk];
            }
            __syncthreads();
            for (int ks = 0; ks < 64; ks += 4) {
                double a = As[w * 16 + mrow][ks + kq];
#pragma unroll
                for (int t = 0; t < 4; ++t) {
                    double bb = Bs[ks + kq][t * 16 + mrow];
                    acc[t] = __builtin_amdgcn_mfma_f64_16x16x4f64(a, bb, acc[t], 0, 0, 0);
                }
            }
            __syncthreads();
        }
#pragma unroll
        for (int t = 0; t < 4; ++t) {
#pragma unroll
            for (int rr = 0; rr < 4; ++rr) {
                int lr, lc; dmap(fl, kq, mrow, rr, lr, lc);
                Zb[(i0 + w * 16 + lr) * 64 + t * 16 + lc] = acc[t][rr];
            }
        }
    } else {
        int c = tid & 63, rg = tid >> 6;
        double acc[16];
#pragma unroll
        for (int r = 0; r < 16; ++r) acc[r] = 0.0;
        for (int k0 = 0; k0 <= i0; k0 += 64) {
            for (int idx = tid; idx < 4096; idx += 256) {
                int r = idx >> 6, kk = idx & 63;
                As[r][kk] = TIb[(i0 + r) * 256 + k0 + kk];
                Bs[r][kk] = Rb[(k0 + r) * 64 + kk];
            }
            __syncthreads();
            for (int kk = 0; kk < 64; ++kk) {
                double bv = Bs[kk][c];
#pragma unroll
                for (int r = 0; r < 16; ++r)
                    acc[r] += As[rg * 16 + r][kk] * bv;
            }
            __syncthreads();
        }
#pragma unroll
        for (int r = 0; r < 16; ++r)
            Zb[(i0 + rg * 16 + r) * 64 + c] = acc[r];
    }
}

// ---------------------------------------------------------------------------
// K4b: M = Tinv^T @ Z  (dual-path, 64-row tiles, triangular k-skip)
// ---------------------------------------------------------------------------
__global__ __launch_bounds__(256) void k_gemm_M(const double* __restrict__ TI,
                                                const double* __restrict__ Z,
                                                double* __restrict__ M,
                                                const double* __restrict__ FLAGD) {
    __shared__ double As[64][65];   // [k][m]
    __shared__ double Bs[64][65];   // [k][c]
    int b = blockIdx.x, i0 = blockIdx.y * 64;
    int tid = threadIdx.x;
    const double* TIb = TI + b * 65536;
    const double* Zb = Z + b * 16384;
    double* Mb = M + b * 16384;
    int fl = (int)FLAGD[0];
    if (fl < 4) {
        int lane = tid & 63, w = tid >> 6;
        int mrow = lane & 15, kq = lane >> 4;
        v4df acc[4];
#pragma unroll
        for (int t = 0; t < 4; ++t) acc[t] = (v4df){0.0, 0.0, 0.0, 0.0};
        for (int k0 = i0; k0 < 256; k0 += 64) {
            for (int idx = tid; idx < 4096; idx += 256) {
                int kk = idx >> 6, m = idx & 63;
                As[kk][m] = TIb[(k0 + kk) * 256 + i0 + m];
                Bs[kk][m] = Zb[(k0 + kk) * 64 + m];
            }
            __syncthreads();
            for (int ks = 0; ks < 64; ks += 4) {
                double a = As[ks + kq][w * 16 + mrow];
#pragma unroll
                for (int t = 0; t < 4; ++t) {
                    double bb = Bs[ks + kq][t * 16 + mrow];
                    acc[t] = __builtin_amdgcn_mfma_f64_16x16x4f64(a, bb, acc[t], 0, 0, 0);
                }
            }
            __syncthreads();
        }
#pragma unroll
        for (int t = 0; t < 4; ++t) {
#pragma unroll
            for (int rr = 0; rr < 4; ++rr) {
                int lr, lc; dmap(fl, kq, mrow, rr, lr, lc);
                Mb[(i0 + w * 16 + lr) * 64 + t * 16 + lc] = acc[t][rr];
            }
        }
    } else {
        int c = tid & 63, rg = tid >> 6;
        double acc[16];
#pragma unroll
        for (int r = 0; r < 16; ++r) acc[r] = 0.0;
        for (int k0 = i0; k0 < 256; k0 += 64) {
            for (int idx = tid; idx < 4096; idx += 256) {
                int kk = idx >> 6, m = idx & 63;
                As[kk][m] = TIb[(k0 + kk) * 256 + i0 + m];
                Bs[kk][m] = Zb[(k0 + kk) * 64 + m];
            }
            __syncthreads();
            for (int kk = 0; kk < 64; ++kk) {
                double bv = Bs[kk][c];
#pragma unroll
                for (int r = 0; r < 16; ++r)
                    acc[r] += As[kk][rg * 16 + r] * bv;
            }
            __syncthreads();
        }
#pragma unroll
        for (int r = 0; r < 16; ++r)
            Mb[(i0 + rg * 16 + r) * 64 + c] = acc[r];
    }
}

// ---------------------------------------------------------------------------
// K5: W = PhiQ @ TinvF^T, PSUM[b][I][q] = sum_{i in I-tile} W[q][i]^2 (fp32)
// ---------------------------------------------------------------------------
__global__ __launch_bounds__(256) void k_spread_gemm(const float* __restrict__ PHIQ,
                                                     const float* __restrict__ TIF,
                                                     float* __restrict__ PSUM) {
    __shared__ float Qs[64][65];
    __shared__ float Ts[64][65];
    int b = blockIdx.x, q0 = blockIdx.y * 64, I = blockIdx.z, i0 = I * 64;
    int tid = threadIdx.x, tx = tid & 15, ty = tid >> 4;
    const float* Qb = PHIQ + b * (NQ * DIN) + q0 * DIN;
    const float* Tb = TIF + b * 65536;
    float acc[4][4];
#pragma unroll
    for (int r = 0; r < 4; ++r)
#pragma unroll
        for (int s = 0; s < 4; ++s) acc[r][s] = 0.0f;
    for (int k0 = 0; k0 <= i0; k0 += 64) {
        for (int idx = tid; idx < 4096; idx += 256) {
            int r = idx >> 6, c = idx & 63;
            Qs[r][c] = Qb[r * 256 + k0 + c];
            Ts[c][r] = Tb[(i0 + r) * 256 + k0 + c];
        }
        __syncthreads();
        for (int kk = 0; kk < 64; ++kk) {
            float a0 = Qs[4 * ty + 0][kk], a1 = Qs[4 * ty + 1][kk];
            float a2 = Qs[4 * ty + 2][kk], a3 = Qs[4 * ty + 3][kk];
            float b0 = Ts[kk][4 * tx + 0], b1 = Ts[kk][4 * tx + 1];
            float b2 = Ts[kk][4 * tx + 2], b3 = Ts[kk][4 * tx + 3];
            acc[0][0] += a0 * b0; acc[0][1] += a0 * b1; acc[0][2] += a0 * b2; acc[0][3] += a0 * b3;
            acc[1][0] += a1 * b0; acc[1][1] += a1 * b1; acc[1][2] += a1 * b2; acc[1][3] += a1 * b3;
            acc[2][0] += a2 * b0; acc[2][1] += a2 * b1; acc[2][2] += a2 * b2; acc[2][3] += a2 * b3;
            acc[3][0] += a3 * b0; acc[3][1] += a3 * b1; acc[3][2] += a3 * b2; acc[3][3] += a3 * b3;
        }
        __syncthreads();
    }
#pragma unroll
    for (int r = 0; r < 4; ++r) {
        float p = acc[r][0] * acc[r][0] + acc[r][1] * acc[r][1]
                + acc[r][2] * acc[r][2] + acc[r][3] * acc[r][3];
        p += __shfl_down(p, 8, 16);
        p += __shfl_down(p, 4, 16);
        p += __shfl_down(p, 2, 16);
        p += __shfl_down(p, 1, 16);
        if (tx == 0) PSUM[(size_t)(b * 4 + I) * 512 + q0 + 4 * ty + r] = p;
    }
}

// ---------------------------------------------------------------------------
// K6: mu = Phi_q @ m (fp32), FUSED epilogue: spread combine + nll partial.
// ---------------------------------------------------------------------------
__global__ __launch_bounds__(256) void k_mu_nll(const float* __restrict__ PHIQ,
                                                const double* __restrict__ M,
                                                const float* __restrict__ YQ,
                                                const float* __restrict__ PSUM,
                                                const float* __restrict__ SE,
                                                float* __restrict__ SPREAD,
                                                double* __restrict__ NLLACC,
                                                float* __restrict__ MU) {
    __shared__ float Qs[64][65];
    __shared__ float Ms[64][64];
    __shared__ double nred[64];
    int b = blockIdx.x, q0 = blockIdx.y * 64, tid = threadIdx.x;
    int tx = tid & 15, ty = tid >> 4;
    const float* Qb = PHIQ + b * (NQ * DIN) + q0 * DIN;
    const double* Mb = M + b * 16384;
    float acc[4][4];
#pragma unroll
    for (int r = 0; r < 4; ++r)
#pragma unroll
        for (int s = 0; s < 4; ++s) acc[r][s] = 0.0f;
    for (int c0 = 0; c0 < 256; c0 += 64) {
        for (int idx = tid; idx < 4096; idx += 256) {
            int r = idx >> 6, c = idx & 63;
            Qs[r][c] = Qb[r * 256 + c0 + c];
            Ms[r][c] = (float)Mb[(c0 + r) * 64 + c];
        }
        __syncthreads();
        for (int kk = 0; kk < 64; ++kk) {
            float a0 = Qs[4 * ty + 0][kk], a1 = Qs[4 * ty + 1][kk];
            float a2 = Qs[4 * ty + 2][kk], a3 = Qs[4 * ty + 3][kk];
            float b0 = Ms[kk][4 * tx + 0], b1 = Ms[kk][4 * tx + 1];
            float b2 = Ms[kk][4 * tx + 2], b3 = Ms[kk][4 * tx + 3];
            acc[0][0] += a0 * b0; acc[0][1] += a0 * b1; acc[0][2] += a0 * b2; acc[0][3] += a0 * b3;
            acc[1][0] += a1 * b0; acc[1][1] += a1 * b1; acc[1][2] += a1 * b2; acc[1][3] += a1 * b3;
            acc[2][0] += a2 * b0; acc[2][1] += a2 * b1; acc[2][2] += a2 * b2; acc[2][3] += a2 * b3;
            acc[3][0] += a3 * b0; acc[3][1] += a3 * b1; acc[3][2] += a3 * b2; acc[3][3] += a3 * b3;
        }
        __syncthreads();
    }
    float se = SE[0];
#pragma unroll
    for (int r = 0; r < 4; ++r) {
        int q = q0 + 4 * ty + r;
        float4 v = make_float4(acc[r][0], acc[r][1], acc[r][2], acc[r][3]);
        *(float4*)&MU[(b * NQ + q) * 64 + 4 * tx] = v;
        float4 y = *(const float4*)&YQ[(size_t)(b * NQ + q) * 64 + 4 * tx];
        float dx = y.x - v.x, dy = y.y - v.y, dz = y.z - v.z, dw = y.w - v.w;
        float qs = dx * dx + dy * dy + dz * dz + dw * dw;
        qs += __shfl_down(qs, 8, 16);
        qs += __shfl_down(qs, 4, 16);
        qs += __shfl_down(qs, 2, 16);
        qs += __shfl_down(qs, 1, 16);
        if (tx == 0) {
            float sp = 1.0f + PSUM[(size_t)(b * 4 + 0) * 512 + q]
                            + PSUM[(size_t)(b * 4 + 1) * 512 + q]
                            + PSUM[(size_t)(b * 4 + 2) * 512 + q]
                            + PSUM[(size_t)(b * 4 + 3) * 512 + q];
            SPREAD[b * 512 + q] = sp;
            float val = 64.0f * (logf(sp) + logf(se)) + qs / (sp * se);
            nred[ty * 4 + r] = (double)val;
        }
    }
    __syncthreads();
    for (int s = 32; s > 0; s >>= 1) {
        if (tid < s) nred[tid] += nred[tid + s];
        __syncthreads();
    }
    if (tid == 0) atomicAdd(NLLACC, nred[0] * (1.0 / 65536.0));
}

// ---------------------------------------------------------------------------
// K6b: write nll scalar
// ---------------------------------------------------------------------------
__global__ void k_nll_final(const double* __restrict__ NLLACC,
                            float* __restrict__ out) {
    if (threadIdx.x == 0) out[NLL_IDX] = (float)NLLACC[0];
}

// ---------------------------------------------------------------------------
// K7 (runs LAST): stream sig; fully overwrites scratch inside d_out sig region.
// ---------------------------------------------------------------------------
__global__ __launch_bounds__(256) void k_sig(const float* __restrict__ SPREAD,
                                             const float* __restrict__ SE,
                                             float* __restrict__ out) {
    __shared__ float sv_s;
    int bq = blockIdx.x, tid = threadIdx.x;
    if (tid == 0) sv_s = SPREAD[bq] * SE[0];
    __syncthreads();
    float sv = sv_s;
    float* base = out + (size_t)MU_SIZE + (size_t)bq * 4096;
    int i = tid >> 2;
    int jb = (tid & 3) << 4;
    int d = i - jb;
    float vals[16];
#pragma unroll
    for (int t = 0; t < 16; ++t) vals[t] = (t == d) ? sv : 0.0f;
    float4* p = (float4*)(base + tid * 16);
    p[0] = make_float4(vals[0], vals[1], vals[2], vals[3]);
    p[1] = make_float4(vals[4], vals[5], vals[6], vals[7]);
    p[2] = make_float4(vals[8], vals[9], vals[10], vals[11]);
    p[3] = make_float4(vals[12], vals[13], vals[14], vals[15]);
}

// ---------------------------------------------------------------------------
extern "C" void kernel_launch(void* const* d_in, const int* in_sizes, int n_in,
                              void* d_out, int out_size, void* d_ws, size_t ws_size,
                              hipStream_t stream) {
    const float* PHI_S = (const float*)d_in[0];
    const float* Y_S   = (const float*)d_in[1];
    const float* PHI_Q = (const float*)d_in[2];
    const float* Y_Q   = (const float*)d_in[3];
    const float* MP    = (const float*)d_in[4];
    const float* AP    = (const float*)d_in[5];
    const float* SE    = (const float*)d_in[6];
    float* out = (float*)d_out;

    // Big scratch inside sig region of d_out (dead before k_sig runs last).
    double* scratch = (double*)(out + MU_SIZE);
    double* G    = scratch;                    // 8,388,608 dbl (64 MB)
    double* LT   = G + 8388608;                // 8,388,608 dbl
    double* RHS  = LT + 8388608;               // 2,097,152 dbl (-> becomes M)
    double* Z    = RHS + 2097152;              // 2,097,152 dbl
    double* TI   = Z + 2097152;                // 8,388,608 dbl
    double* Spd  = TI + 8388608;               // 65,536 dbl
    double* MPN  = Spd + 65536;                // 16,384 dbl
    double* LI   = MPN + 16384;                // 2,097,152 dbl (16 MB, L11inv)
    float*  TIF  = (float*)(LI + 2097152);     // 8,388,608 f32 (32 MB)
    float*  PSUM = TIF + 8388608;              // 262,144 f32 (1 MB)
    // Small persistent scratch (survives until k_sig) in d_ws (proven 258 KB).
    float*  SPREAD = (float*)d_ws;                           // 65,536 f32
    double* NLLACC = (double*)((char*)d_ws + 65536 * 4);     // 1 dbl
    double* FLAGD  = (double*)((char*)d_ws + 65536 * 4 + 8); // 1 dbl

    k_mfma_probe <<<1, 64, 0, stream>>>(FLAGD);
    k_prior_sp   <<<256, 256, 0, stream>>>(AP, Spd, NLLACC);
    k_prior_mpn  <<<256, 64, 0, stream>>>(Spd, MP, MPN);
    k_build_G    <<<dim3(B_T, 10), 256, 0, stream>>>(PHI_S, Spd, G, FLAGD);
    k_build_rhs  <<<dim3(B_T, 4), 256, 0, stream>>>(PHI_S, Y_S, MPN, RHS, FLAGD);
    // fused per-task blocked Cholesky (replaces 10-dispatch chain)
    k_cholf      <<<B_T, 256, 0, stream>>>(G, LT, LI);
    k_tidiag     <<<B_T, 256, 0, stream>>>(LI, TI, TIF);
    k_trinv64    <<<dim3(B_T, 3), 256, 0, stream>>>(LT, LI, TI, TIF);
    k_gemm_Z     <<<dim3(B_T, 4), 256, 0, stream>>>(TI, RHS, Z, FLAGD);
    k_gemm_M     <<<dim3(B_T, 4), 256, 0, stream>>>(TI, Z, RHS, FLAGD);
    k_spread_gemm<<<dim3(B_T, 8, 4), 256, 0, stream>>>(PHI_Q, TIF, PSUM);
    k_mu_nll     <<<dim3(B_T, 8), 256, 0, stream>>>(PHI_Q, RHS, Y_Q, PSUM, SE,
                                                    SPREAD, NLLACC, out);
    k_nll_final  <<<1, 64, 0, stream>>>(NLLACC, out);
    k_sig        <<<65536, 256, 0, stream>>>(SPREAD, SE, out);   // LAST
}